// Round 5
// baseline (753.713 us; speedup 1.0000x reference)
//
#include <hip/hip_runtime.h>
#include <math.h>

#define ATOM_FEA 128
#define NBR_FEA  64
#define IN_DIM   320   // 2*ATOM_FEA + NBR_FEA
#define OUT_DIM  256   // 2*ATOM_FEA

#define M_TILE   48    // edges per tile = exactly 4 nodes (48 = 4*12)
#define GRID_G   1024  // k2 persistent grid: 4 blocks/CU (VGPR<128 -> 4 waves/SIMD)
#define GRID_3   2048  // k3 grid
#define RB1      32    // stage-1 reduce blocks

#define X_STR    528   // 256 ch * 2B + 16B pad (full-BW LDS access)
#define SMEMX    (M_TILE * X_STR)   // 25344 B

typedef float  f32x4 __attribute__((ext_vector_type(4)));
typedef short  s16x8 __attribute__((ext_vector_type(8)));   // 8 bf16

__device__ __forceinline__ float softplusf(float v) {
    float e = __expf(-fabsf(v));
    return fmaxf(v, 0.f) + __logf(1.f + e);
}
__device__ __forceinline__ float sigmoidf(float v) {
    return __builtin_amdgcn_rcpf(1.f + __expf(-v));
}
__device__ __forceinline__ float bf2f(unsigned short h) {
    return __uint_as_float(((unsigned)h) << 16);
}
// packed f32->bf16 (RNE) pair: lo = bf16(a), hi = bf16(b)
__device__ __forceinline__ unsigned pk2(float a, float b) {
    unsigned r;
    asm("v_cvt_pk_bf16_f32 %0, %1, %2" : "=v"(r) : "v"(a), "v"(b));
    return r;
}

// ---------------------------------------------------------------------------
// K1 (MFMA, transposed epilogue): A[n,c]=W[c,0:128]·x[n],
// B[n,c]=W[c,128:256]·x[n] + b[c]  (bias folded in f32 before the single
// bf16 rounding).
// ---------------------------------------------------------------------------
__global__ __launch_bounds__(256) void k1_mfma(
    const float* __restrict__ x, const float* __restrict__ W,
    const float* __restrict__ bvec,
    unsigned short* __restrict__ Abf, unsigned short* __restrict__ Bbf,
    int nNodes)
{
    __shared__ alignas(16) char sx[64 * 272];   // 64 rows x 128 bf16 (256B) + 16B pad
    const int tid  = threadIdx.x;
    const int wave = tid >> 6;
    const int lane = tid & 63;
    const int li   = lane & 15;
    const int quad = lane >> 4;
    const int cTile = blockIdx.x * 64;          // 0..448
    const int nTile = blockIdx.y * 64;
    const int cOff  = (cTile < 256) ? cTile : (cTile - 256);
    const int kBase = (cTile < 256) ? 0 : 128;
    unsigned short* dst = (cTile < 256) ? Abf : Bbf;

    // W fragments (A-operand: row = ch = cOff+ns*16+li, k = ks*32+quad*8)
    s16x8 bf[4][4];
    #pragma unroll
    for (int ks = 0; ks < 4; ++ks)
        #pragma unroll
        for (int ns = 0; ns < 4; ++ns) {
            const float* wr = W + (size_t)(cOff + ns * 16 + li) * IN_DIM + kBase + ks * 32 + quad * 8;
            float4 va = *(const float4*)wr;
            float4 vb = *(const float4*)(wr + 4);
            union { uint4 u; s16x8 v; } cv;
            cv.u = make_uint4(pk2(va.x, va.y), pk2(va.z, va.w),
                              pk2(vb.x, vb.y), pk2(vb.z, vb.w));
            bf[ks][ns] = cv.v;
        }

    // stage x tile (fp32 -> bf16): 64 rows x 128 floats
    #pragma unroll
    for (int i = 0; i < 8; ++i) {
        int idx = tid + i * 256;        // 0..2047 = 64 rows x 32 quads
        int r = idx >> 5, q = idx & 31;
        int gn = nTile + r;
        float4 v = make_float4(0.f, 0.f, 0.f, 0.f);
        if (gn < nNodes) v = *(const float4*)(x + (size_t)gn * ATOM_FEA + q * 4);
        uint2 u; u.x = pk2(v.x, v.y); u.y = pk2(v.z, v.w);
        *(uint2*)(sx + r * 272 + q * 8) = u;
    }
    __syncthreads();

    // x fragments (B-operand: col = node = li, k = quad*8)
    s16x8 af[4];
    #pragma unroll
    for (int ks = 0; ks < 4; ++ks)
        af[ks] = *(const s16x8*)(sx + (wave * 16 + li) * 272 + (ks * 32 + quad * 8) * 2);

    f32x4 acc[4] = {};
    #pragma unroll
    for (int ks = 0; ks < 4; ++ks)
        #pragma unroll
        for (int ns = 0; ns < 4; ++ns)
            acc[ns] = __builtin_amdgcn_mfma_f32_16x16x32_bf16(bf[ks][ns], af[ks], acc[ns], 0, 0, 0);

    // D[ch = ns*16+quad*4+r][node = wave*16+li]
    const int node = nTile + wave * 16 + li;
    if (node < nNodes) {
        #pragma unroll
        for (int ns = 0; ns < 4; ++ns) {
            const int c0 = cOff + ns * 16 + quad * 4;
            float4 bb = make_float4(0.f, 0.f, 0.f, 0.f);
            if (kBase) bb = *(const float4*)(bvec + c0);
            uint2 o;
            o.x = pk2(acc[ns][0] + bb.x, acc[ns][1] + bb.y);
            o.y = pk2(acc[ns][2] + bb.z, acc[ns][3] + bb.w);
            *(uint2*)(dst + (size_t)node * 256 + c0) = o;
        }
    }
}

// ---------------------------------------------------------------------------
// K2 (hybrid): phase-1 = direct-from-global ea frags + mfma(W, ea) ->
// lane holds 4 consecutive ch of one edge -> 12 conflict-free ds_write_b64
// into X tile.  Barrier.  Phase-2 = wave owns node t*4+wave: wave-uniform
// 512B A-row gathers (batched x12), LDS X read, +B(bias folded), BN1
// partials, 512B coalesced store.  All global accesses coalesced.
// ---------------------------------------------------------------------------
__global__ __launch_bounds__(256) void k2_fused(
    const unsigned short* __restrict__ Abf, const unsigned short* __restrict__ Bbf,
    const float* __restrict__ ea, const int* __restrict__ ei,
    const float* __restrict__ W,
    unsigned short* __restrict__ gated, float* __restrict__ part,
    int nNodes, int nEdges)
{
    __shared__ alignas(16) char smem[SMEMX];
    const int tid  = threadIdx.x;
    const int wave = tid >> 6;
    const int lane = tid & 63;
    const int li   = lane & 15;
    const int quad = lane >> 4;

    // We fragments (A-operand: row = ch = wave*64+ns*16+li, k = ks*32+quad*8)
    s16x8 bfr[2][4];
    #pragma unroll
    for (int ks = 0; ks < 2; ++ks)
        #pragma unroll
        for (int ns = 0; ns < 4; ++ns) {
            int chn = wave * 64 + ns * 16 + li;
            const float* wr = W + (size_t)chn * IN_DIM + 256 + ks * 32 + quad * 8;
            float4 va = *(const float4*)wr;
            float4 vb = *(const float4*)(wr + 4);
            union { uint4 u; s16x8 v; } cv;
            cv.u = make_uint4(pk2(va.x, va.y), pk2(va.z, va.w),
                              pk2(vb.x, vb.y), pk2(vb.z, vb.w));
            bfr[ks][ns] = cv.v;
        }

    const int cB  = wave * 64 + quad * 4;   // phase-1 channel base (+ ns*16)
    const int chq = lane;                   // phase-2: lane covers ch 4*lane..4*lane+3

    f32x4 s4  = {0.f, 0.f, 0.f, 0.f};
    f32x4 s24 = {0.f, 0.f, 0.f, 0.f};

    const int nTiles = (nEdges + M_TILE - 1) / M_TILE;
    for (int t = blockIdx.x; t < nTiles; t += gridDim.x) {
        const int tBase = t * M_TILE;
        const int node  = t * 4 + wave;     // phase-2 node for this wave
        const bool okN  = (node < nNodes);

        // neighbor indices for this wave's 12 edges (wave-uniform addresses)
        int nbj[12];
        #pragma unroll
        for (int j = 0; j < 12; ++j)
            nbj[j] = okN ? ei[nEdges + node * 12 + j] : 0;

        // ---- phase 1: MFMA over 3 sub-tiles of 16 edges ----
        f32x4 acc[3][4] = {};
        #pragma unroll
        for (int ms = 0; ms < 3; ++ms) {
            const int e   = tBase + ms * 16 + li;
            const bool ok = (e < nEdges);
            s16x8 af[2];
            #pragma unroll
            for (int ks = 0; ks < 2; ++ks) {
                float4 va = make_float4(0.f, 0.f, 0.f, 0.f);
                float4 vb = make_float4(0.f, 0.f, 0.f, 0.f);
                if (ok) {
                    const float* er = ea + (size_t)e * NBR_FEA + ks * 32 + quad * 8;
                    va = *(const float4*)er;
                    vb = *(const float4*)(er + 4);
                }
                union { uint4 u; s16x8 v; } cv;
                cv.u = make_uint4(pk2(va.x, va.y), pk2(va.z, va.w),
                                  pk2(vb.x, vb.y), pk2(vb.z, vb.w));
                af[ks] = cv.v;
            }
            #pragma unroll
            for (int ks = 0; ks < 2; ++ks)
                #pragma unroll
                for (int ns = 0; ns < 4; ++ns)
                    acc[ms][ns] = __builtin_amdgcn_mfma_f32_16x16x32_bf16(
                        bfr[ks][ns], af[ks], acc[ms][ns], 0, 0, 0);
        }

        __syncthreads();   // B0: previous tile's X reads complete

        // X exchange write: row = edge-in-tile, col = channel (bf16 packed)
        #pragma unroll
        for (int ms = 0; ms < 3; ++ms)
            #pragma unroll
            for (int ns = 0; ns < 4; ++ns) {
                const int row = ms * 16 + li;
                uint2 o;
                o.x = pk2(acc[ms][ns][0], acc[ms][ns][1]);
                o.y = pk2(acc[ms][ns][2], acc[ms][ns][3]);
                *(uint2*)(smem + row * X_STR + (cB + ns * 16) * 2) = o;
            }

        __syncthreads();   // B1: X complete

        // ---- phase 2: wave-uniform, fully coalesced epilogue ----
        if (okN) {
            uint2 bn2 = *(const uint2*)(Bbf + (size_t)node * 256 + chq * 4);
            const float Bn0 = bf2f((unsigned short)(bn2.x & 0xffffu));
            const float Bn1 = bf2f((unsigned short)(bn2.x >> 16));
            const float Bn2 = bf2f((unsigned short)(bn2.y & 0xffffu));
            const float Bn3 = bf2f((unsigned short)(bn2.y >> 16));

            // batch all 12 A-row gathers (each wave-uniform: 512B coalesced)
            uint2 a2[12];
            #pragma unroll
            for (int j = 0; j < 12; ++j)
                a2[j] = *(const uint2*)(Abf + (size_t)nbj[j] * 256 + chq * 4);

            #pragma unroll
            for (int j = 0; j < 12; ++j) {
                const int e = node * 12 + j;
                uint2 xv = *(const uint2*)(smem + (wave * 12 + j) * X_STR + chq * 8);
                float g0 = bf2f((unsigned short)(xv.x & 0xffffu)) + bf2f((unsigned short)(a2[j].x & 0xffffu)) + Bn0;
                float g1 = bf2f((unsigned short)(xv.x >> 16))     + bf2f((unsigned short)(a2[j].x >> 16))     + Bn1;
                float g2 = bf2f((unsigned short)(xv.y & 0xffffu)) + bf2f((unsigned short)(a2[j].y & 0xffffu)) + Bn2;
                float g3 = bf2f((unsigned short)(xv.y >> 16))     + bf2f((unsigned short)(a2[j].y >> 16))     + Bn3;
                s4[0] += g0; s4[1] += g1; s4[2] += g2; s4[3] += g3;
                s24[0] = fmaf(g0, g0, s24[0]); s24[1] = fmaf(g1, g1, s24[1]);
                s24[2] = fmaf(g2, g2, s24[2]); s24[3] = fmaf(g3, g3, s24[3]);
                uint2 o; o.x = pk2(g0, g1); o.y = pk2(g2, g3);
                *(uint2*)(gated + (size_t)e * 256 + chq * 4) = o;
            }
        }
    }

    // block-level BN1 partial reduce (each wave covers all 256 ch)
    __syncthreads();
    float* red = (float*)smem;
    *(f32x4*)(red + (size_t)(wave * 64 + chq) * 8)     = s4;
    *(f32x4*)(red + (size_t)(wave * 64 + chq) * 8 + 4) = s24;
    __syncthreads();
    {
        const int c = tid;
        const int g = c >> 2, k = c & 3;
        float s = 0.f, s2 = 0.f;
        #pragma unroll
        for (int w = 0; w < 4; ++w) {
            s  += red[(w * 64 + g) * 8 + k];
            s2 += red[(w * 64 + g) * 8 + 4 + k];
        }
        part[(size_t)blockIdx.x * 512 + c]       = s;
        part[(size_t)blockIdx.x * 512 + 256 + c] = s2;
    }
}

// ---- two-stage BN1 reduce -------------------------------------------------
__global__ __launch_bounds__(512) void k2b1(
    const float* __restrict__ part, float* __restrict__ out, int nRows, int rowsPerBlk)
{
    const int c = threadIdx.x;
    int r0 = blockIdx.x * rowsPerBlk;
    int r1 = min(r0 + rowsPerBlk, nRows);
    float s = 0.f;
    for (int r = r0; r < r1; ++r) s += part[(size_t)r * 512 + c];
    out[(size_t)blockIdx.x * 512 + c] = s;
}
__global__ __launch_bounds__(256) void k2b2(
    const float* __restrict__ p1, const float* __restrict__ g1v,
    const float* __restrict__ b1v, float* __restrict__ stats, float invE)
{
    const int c = threadIdx.x;
    float s = 0.f, s2 = 0.f;
    for (int r = 0; r < RB1; ++r) {
        s  += p1[(size_t)r * 512 + c];
        s2 += p1[(size_t)r * 512 + 256 + c];
    }
    float mean = s * invE;
    float var = fmaf(-mean, mean, s2 * invE);
    float sc = g1v[c] * rsqrtf(var + 1e-5f);
    stats[c] = sc;
    stats[256 + c] = fmaf(-mean, sc, b1v[c]);
}

// ---------------------------------------------------------------------------
// K3: elementwise over stored bf16 gated: BN1 affine -> sigmoid*softplus ->
// 12-edge node sum -> NS + BN2 partials.
// ---------------------------------------------------------------------------
__global__ __launch_bounds__(256) void k3_msg2(
    const unsigned short* __restrict__ gated, const float* __restrict__ stats,
    float* __restrict__ NS, float* __restrict__ part2, int nNodes)
{
    const int tid = threadIdx.x;
    const int o  = tid & 15;
    const int nl = tid >> 4;
    float scF[8], shF[8], scC[8], shC[8];
    #pragma unroll
    for (int k = 0; k < 8; ++k) {
        int cf = o * 8 + k;
        scF[k] = stats[cf];        shF[k] = stats[256 + cf];
        scC[k] = stats[128 + cf];  shC[k] = stats[384 + cf];
    }
    float sA[8] = {}, s2A[8] = {};
    for (int n = blockIdx.x * 16 + nl; n < nNodes; n += gridDim.x * 16) {
        float m[8] = {};
        for (int j = 0; j < 12; ++j) {
            size_t base = (size_t)(n * 12 + j) * 256;
            uint4 uf = *(const uint4*)(gated + base + o * 8);
            uint4 uc = *(const uint4*)(gated + base + 128 + o * 8);
            unsigned fu[4] = {uf.x, uf.y, uf.z, uf.w};
            unsigned cu[4] = {uc.x, uc.y, uc.z, uc.w};
            #pragma unroll
            for (int q = 0; q < 4; ++q) {
                float f0 = fmaf(bf2f((unsigned short)(fu[q] & 0xffffu)), scF[q*2],   shF[q*2]);
                float f1 = fmaf(bf2f((unsigned short)(fu[q] >> 16)),     scF[q*2+1], shF[q*2+1]);
                float c0 = fmaf(bf2f((unsigned short)(cu[q] & 0xffffu)), scC[q*2],   shC[q*2]);
                float c1 = fmaf(bf2f((unsigned short)(cu[q] >> 16)),     scC[q*2+1], shC[q*2+1]);
                m[q*2]   = fmaf(sigmoidf(f0), softplusf(c0), m[q*2]);
                m[q*2+1] = fmaf(sigmoidf(f1), softplusf(c1), m[q*2+1]);
            }
        }
        float4 o0 = {m[0], m[1], m[2], m[3]};
        float4 o1 = {m[4], m[5], m[6], m[7]};
        *(float4*)(NS + (size_t)n * 128 + o * 8)     = o0;
        *(float4*)(NS + (size_t)n * 128 + o * 8 + 4) = o1;
        #pragma unroll
        for (int k = 0; k < 8; ++k) {
            sA[k] += m[k];
            s2A[k] = fmaf(m[k], m[k], s2A[k]);
        }
    }
    __shared__ float red[2][16][128];
    #pragma unroll
    for (int k = 0; k < 8; ++k) {
        red[0][nl][o * 8 + k] = sA[k];
        red[1][nl][o * 8 + k] = s2A[k];
    }
    __syncthreads();
    if (tid < 128) {
        float s = 0.f, s2 = 0.f;
        #pragma unroll
        for (int r = 0; r < 16; ++r) {
            s  += red[0][r][tid];
            s2 += red[1][r][tid];
        }
        part2[(size_t)blockIdx.x * 256 + tid]       = s;
        part2[(size_t)blockIdx.x * 256 + 128 + tid] = s2;
    }
}

// ---- two-stage BN2 reduce -------------------------------------------------
__global__ __launch_bounds__(256) void k3b1(
    const float* __restrict__ part2, float* __restrict__ out, int nRows, int rowsPerBlk)
{
    const int c = threadIdx.x;
    int r0 = blockIdx.x * rowsPerBlk;
    int r1 = min(r0 + rowsPerBlk, nRows);
    float s = 0.f;
    for (int r = r0; r < r1; ++r) s += part2[(size_t)r * 256 + c];
    out[(size_t)blockIdx.x * 256 + c] = s;
}
__global__ __launch_bounds__(128) void k3b2(
    const float* __restrict__ p1, const float* __restrict__ g2v,
    const float* __restrict__ b2v, float* __restrict__ stats2, float invN)
{
    const int c = threadIdx.x;
    float s = 0.f, s2 = 0.f;
    for (int r = 0; r < RB1; ++r) {
        s  += p1[(size_t)r * 256 + c];
        s2 += p1[(size_t)r * 256 + 128 + c];
    }
    float mean = s * invN;
    float var = fmaf(-mean, mean, s2 * invN);
    float sc = g2v[c] * rsqrtf(var + 1e-5f);
    stats2[c] = sc;
    stats2[128 + c] = fmaf(-mean, sc, b2v[c]);
}

// ---------------------------------------------------------------------------
// K4: out = softplus(x + nbr_sumed*scale2 + shift2)
// ---------------------------------------------------------------------------
__global__ __launch_bounds__(256) void k4_final(
    const float* __restrict__ x, const float* __restrict__ ns,
    const float* __restrict__ stats2, float* __restrict__ out, int total4)
{
    int idx = blockIdx.x * 256 + threadIdx.x;
    for (int i = idx; i < total4; i += gridDim.x * 256) {
        int cq = i & 31;
        float4 xv = ((const float4*)x)[i];
        float4 sv = ((const float4*)ns)[i];
        float4 sc = ((const float4*)stats2)[cq];
        float4 sh = ((const float4*)(stats2 + 128))[cq];
        float4 o;
        o.x = softplusf(fmaf(sv.x, sc.x, sh.x) + xv.x);
        o.y = softplusf(fmaf(sv.y, sc.y, sh.y) + xv.y);
        o.z = softplusf(fmaf(sv.z, sc.z, sh.z) + xv.z);
        o.w = softplusf(fmaf(sv.w, sc.w, sh.w) + xv.w);
        ((float4*)out)[i] = o;
    }
}

extern "C" void kernel_launch(void* const* d_in, const int* in_sizes, int n_in,
                              void* d_out, int out_size, void* d_ws, size_t ws_size,
                              hipStream_t stream)
{
    const float* x   = (const float*)d_in[0];
    const int*   ei  = (const int*)d_in[1];
    const float* ea  = (const float*)d_in[2];
    const float* W   = (const float*)d_in[3];
    const float* b   = (const float*)d_in[4];
    const float* g1v = (const float*)d_in[5];
    const float* b1v = (const float*)d_in[6];
    const float* g2v = (const float*)d_in[7];
    const float* b2v = (const float*)d_in[8];
    float* out = (float*)d_out;

    const int nNodes = in_sizes[0] / ATOM_FEA;
    const int nEdges = in_sizes[1] / 2;

    unsigned short* Abf   = (unsigned short*)d_ws;               // nNodes*256 bf16
    unsigned short* Bbf   = Abf + (size_t)nNodes * 256;          // nNodes*256 bf16 (bias folded)
    unsigned short* gated = Bbf + (size_t)nNodes * 256;          // nEdges*256 bf16
    float* NS  = (float*)(gated + (size_t)nEdges * 256);         // nNodes*128
    float* P1  = NS  + (size_t)nNodes * 128;                     // GRID_G*512
    float* P1b = P1  + (size_t)GRID_G * 512;                     // RB1*512
    float* P2  = P1b + (size_t)RB1 * 512;                        // GRID_3*256
    float* P2b = P2  + (size_t)GRID_3 * 256;                     // RB1*256
    float* S1  = P2b + (size_t)RB1 * 256;                        // 512
    float* S2  = S1 + 512;                                       // 256
    (void)ws_size; (void)n_in; (void)out_size;

    dim3 grid1(8, (nNodes + 63) / 64);
    k1_mfma<<<grid1, 256, 0, stream>>>(x, W, b, Abf, Bbf, nNodes);

    k2_fused<<<GRID_G, 256, 0, stream>>>(Abf, Bbf, ea, ei, W, gated, P1, nNodes, nEdges);
    k2b1<<<RB1, 512, 0, stream>>>(P1, P1b, GRID_G, (GRID_G + RB1 - 1) / RB1);
    k2b2<<<1, 256, 0, stream>>>(P1b, g1v, b1v, S1, 1.f / (float)nEdges);
    k3_msg2<<<GRID_3, 256, 0, stream>>>(gated, S1, NS, P2, nNodes);
    k3b1<<<RB1, 256, 0, stream>>>(P2, P2b, GRID_3, (GRID_3 + RB1 - 1) / RB1);
    k3b2<<<1, 128, 0, stream>>>(P2b, g2v, b2v, S2, 1.f / (float)nNodes);
    k4_final<<<2048, 256, 0, stream>>>(x, NS, S2, out, nNodes * 32);
}

// Round 6
// 619.493 us; speedup vs baseline: 1.2167x; 1.2167x over previous
//
#include <hip/hip_runtime.h>
#include <math.h>

#define ATOM_FEA 128
#define NBR_FEA  64
#define IN_DIM   320   // 2*ATOM_FEA + NBR_FEA
#define OUT_DIM  256   // 2*ATOM_FEA

#define M_TILE   48    // edges per tile = exactly 4 nodes (48 = 4*12)
#define GRID_G   768   // k2 persistent grid: 3 blocks/CU resident (baseline)
#define GRID_3   1024  // k3 grid (baseline)
#define RB1      32    // stage-1 reduce blocks

// LDS layout for k2_fused:
#define EA_OFF   0
#define EA_STR   144     // 48 rows ea tile (72 bf16)
#define X_OFF    6912
#define X_STR    528     // 48 rows exchange (256 bf16 + 16B pad, 2-way banks)
#define SMEM2    32256   // 6912 + 48*528

typedef float  f32x4 __attribute__((ext_vector_type(4)));
typedef short  s16x8 __attribute__((ext_vector_type(8)));   // 8 bf16

__device__ __forceinline__ float softplusf(float v) {
    float e = __expf(-fabsf(v));
    return fmaxf(v, 0.f) + __logf(1.f + e);
}
__device__ __forceinline__ float sigmoidf(float v) {
    return __builtin_amdgcn_rcpf(1.f + __expf(-v));
}
__device__ __forceinline__ float bf2f(unsigned short h) {
    return __uint_as_float(((unsigned)h) << 16);
}
// packed f32->bf16 (RNE) pair in ONE instruction: lo = bf16(a), hi = bf16(b)
__device__ __forceinline__ unsigned pk2(float a, float b) {
    unsigned r;
    asm("v_cvt_pk_bf16_f32 %0, %1, %2" : "=v"(r) : "v"(a), "v"(b));
    return r;
}

// ---------------------------------------------------------------------------
// K1 (MFMA, transposed epilogue): A[n,c]=W[c,0:128]·x[n],
// B[n,c]=W[c,128:256]·x[n] + b[c]  (bias folded in f32 before the single
// bf16 rounding).  mfma(W_frag, x_frag) -> lane holds 4 consecutive channels
// of one node -> packed 8B stores.
// ---------------------------------------------------------------------------
__global__ __launch_bounds__(256) void k1_mfma(
    const float* __restrict__ x, const float* __restrict__ W,
    const float* __restrict__ bvec,
    unsigned short* __restrict__ Abf, unsigned short* __restrict__ Bbf,
    int nNodes)
{
    __shared__ alignas(16) char sx[64 * 272];   // 64 rows x 128 bf16 (256B) + 16B pad
    const int tid  = threadIdx.x;
    const int wave = tid >> 6;
    const int lane = tid & 63;
    const int li   = lane & 15;
    const int quad = lane >> 4;
    const int cTile = blockIdx.x * 64;          // 0..448
    const int nTile = blockIdx.y * 64;
    const int cOff  = (cTile < 256) ? cTile : (cTile - 256);
    const int kBase = (cTile < 256) ? 0 : 128;
    unsigned short* dst = (cTile < 256) ? Abf : Bbf;

    // W fragments (A-operand: row = ch = cOff+ns*16+li, k = ks*32+quad*8)
    s16x8 bf[4][4];
    #pragma unroll
    for (int ks = 0; ks < 4; ++ks)
        #pragma unroll
        for (int ns = 0; ns < 4; ++ns) {
            const float* wr = W + (size_t)(cOff + ns * 16 + li) * IN_DIM + kBase + ks * 32 + quad * 8;
            float4 va = *(const float4*)wr;
            float4 vb = *(const float4*)(wr + 4);
            union { uint4 u; s16x8 v; } cv;
            cv.u = make_uint4(pk2(va.x, va.y), pk2(va.z, va.w),
                              pk2(vb.x, vb.y), pk2(vb.z, vb.w));
            bf[ks][ns] = cv.v;
        }

    // stage x tile (fp32 -> bf16): 64 rows x 128 floats
    #pragma unroll
    for (int i = 0; i < 8; ++i) {
        int idx = tid + i * 256;        // 0..2047 = 64 rows x 32 quads
        int r = idx >> 5, q = idx & 31;
        int gn = nTile + r;
        float4 v = make_float4(0.f, 0.f, 0.f, 0.f);
        if (gn < nNodes) v = *(const float4*)(x + (size_t)gn * ATOM_FEA + q * 4);
        uint2 u; u.x = pk2(v.x, v.y); u.y = pk2(v.z, v.w);
        *(uint2*)(sx + r * 272 + q * 8) = u;
    }
    __syncthreads();

    // x fragments (B-operand: col = node = li, k = quad*8)
    s16x8 af[4];
    #pragma unroll
    for (int ks = 0; ks < 4; ++ks)
        af[ks] = *(const s16x8*)(sx + (wave * 16 + li) * 272 + (ks * 32 + quad * 8) * 2);

    f32x4 acc[4] = {};
    #pragma unroll
    for (int ks = 0; ks < 4; ++ks)
        #pragma unroll
        for (int ns = 0; ns < 4; ++ns)
            acc[ns] = __builtin_amdgcn_mfma_f32_16x16x32_bf16(bf[ks][ns], af[ks], acc[ns], 0, 0, 0);

    // D[ch = ns*16+quad*4+r][node = wave*16+li]
    const int node = nTile + wave * 16 + li;
    if (node < nNodes) {
        #pragma unroll
        for (int ns = 0; ns < 4; ++ns) {
            const int c0 = cOff + ns * 16 + quad * 4;
            float4 bb = make_float4(0.f, 0.f, 0.f, 0.f);
            if (kBase) bb = *(const float4*)(bvec + c0);
            uint2 o;
            o.x = pk2(acc[ns][0] + bb.x, acc[ns][1] + bb.y);
            o.y = pk2(acc[ns][2] + bb.z, acc[ns][3] + bb.w);
            *(uint2*)(dst + (size_t)node * 256 + c0) = o;
        }
    }
}

// ---------------------------------------------------------------------------
// K2 (baseline structure, VALU-trimmed): stage ea tile to LDS -> B1 ->
// transposed MFMA (lane holds 4 consecutive ch of one edge) -> 12 packed
// b64 X-exchange writes -> B2 -> wave-uniform coalesced phase-2 with
// hoisted ei reads and batched A-row gathers.  Bias pre-folded into Bbf.
// ---------------------------------------------------------------------------
__global__ __launch_bounds__(256) void k2_fused(
    const unsigned short* __restrict__ Abf, const unsigned short* __restrict__ Bbf,
    const float* __restrict__ ea, const int* __restrict__ ei,
    const float* __restrict__ W,
    unsigned short* __restrict__ gated, float* __restrict__ part,
    int nNodes, int nEdges)
{
    __shared__ alignas(16) char smem[SMEM2];
    const int tid  = threadIdx.x;
    const int wave = tid >> 6;
    const int lane = tid & 63;
    const int li   = lane & 15;
    const int quad = lane >> 4;

    // We fragments (A-operand: row = ch = wave*64+ns*16+li, k = ks*32+quad*8)
    s16x8 bfr[2][4];
    #pragma unroll
    for (int ks = 0; ks < 2; ++ks)
        #pragma unroll
        for (int ns = 0; ns < 4; ++ns) {
            int chn = wave * 64 + ns * 16 + li;
            const float* wr = W + (size_t)chn * IN_DIM + 256 + ks * 32 + quad * 8;
            float4 va = *(const float4*)wr;
            float4 vb = *(const float4*)(wr + 4);
            union { uint4 u; s16x8 v; } cv;
            cv.u = make_uint4(pk2(va.x, va.y), pk2(va.z, va.w),
                              pk2(vb.x, vb.y), pk2(vb.z, vb.w));
            bfr[ks][ns] = cv.v;
        }

    const int cB  = wave * 64 + quad * 4;   // phase-1 channel base (+ ns*16)
    const int chq = lane;                   // phase-2: lane covers ch 4*lane..4*lane+3

    float4 s4  = {0.f, 0.f, 0.f, 0.f};
    float4 s24 = {0.f, 0.f, 0.f, 0.f};

    const int nTiles = (nEdges + M_TILE - 1) / M_TILE;
    for (int t = blockIdx.x; t < nTiles; t += gridDim.x) {
        const int tBase = t * M_TILE;
        const int node  = t * 4 + wave;     // phase-2 node for this wave
        const bool okN  = (node < nNodes);

        // hoisted neighbor indices (wave-uniform -> scalar loads, long slack)
        int nbj[12];
        #pragma unroll
        for (int j = 0; j < 12; ++j)
            nbj[j] = okN ? ei[nEdges + node * 12 + j] : 0;

        // stage ea tile (fp32 -> bf16 via cvt_pk)
        #pragma unroll
        for (int i = 0; i < 3; ++i) {
            int idx = tid + i * 256;
            int r = idx >> 4, q = idx & 15;
            int ge = tBase + r;
            float4 v = make_float4(0.f, 0.f, 0.f, 0.f);
            if (ge < nEdges) v = *(const float4*)(ea + (size_t)ge * 64 + q * 4);
            uint2 u; u.x = pk2(v.x, v.y); u.y = pk2(v.z, v.w);
            *(uint2*)(smem + EA_OFF + r * EA_STR + q * 8) = u;
        }
        __syncthreads();   // B1 (also fences prev-iter X reads)

        s16x8 af[2][3];
        #pragma unroll
        for (int ks = 0; ks < 2; ++ks)
            #pragma unroll
            for (int ms = 0; ms < 3; ++ms)
                af[ks][ms] = *(const s16x8*)(smem + EA_OFF + (ms * 16 + li) * EA_STR + (ks * 32 + quad * 8) * 2);

        f32x4 acc[3][4] = {};
        #pragma unroll
        for (int ks = 0; ks < 2; ++ks)
            #pragma unroll
            for (int ms = 0; ms < 3; ++ms)
                #pragma unroll
                for (int ns = 0; ns < 4; ++ns)
                    acc[ms][ns] = __builtin_amdgcn_mfma_f32_16x16x32_bf16(
                        bfr[ks][ns], af[ks][ms], acc[ms][ns], 0, 0, 0);

        // X exchange: row = edge-in-tile, lane owns 4 consecutive ch -> b64
        #pragma unroll
        for (int ms = 0; ms < 3; ++ms)
            #pragma unroll
            for (int ns = 0; ns < 4; ++ns) {
                const int row = ms * 16 + li;
                uint2 o;
                o.x = pk2(acc[ms][ns][0], acc[ms][ns][1]);
                o.y = pk2(acc[ms][ns][2], acc[ms][ns][3]);
                *(uint2*)(smem + X_OFF + row * X_STR + (cB + ns * 16) * 2) = o;
            }
        __syncthreads();   // B2

        // phase 2: wave owns node; lanes cover 256 ch (4 each), all coalesced
        if (okN) {
            uint2 bn2 = *(const uint2*)(Bbf + (size_t)node * 256 + chq * 4);
            const float Bn0 = bf2f((unsigned short)(bn2.x & 0xffffu));
            const float Bn1 = bf2f((unsigned short)(bn2.x >> 16));
            const float Bn2 = bf2f((unsigned short)(bn2.y & 0xffffu));
            const float Bn3 = bf2f((unsigned short)(bn2.y >> 16));

            // batched wave-uniform 512B A-row gathers (12 independent loads)
            uint2 a2[12];
            #pragma unroll
            for (int j = 0; j < 12; ++j)
                a2[j] = *(const uint2*)(Abf + (size_t)nbj[j] * 256 + chq * 4);

            #pragma unroll
            for (int j = 0; j < 12; ++j) {
                const int e = node * 12 + j;
                uint2 xv = *(const uint2*)(smem + X_OFF + (wave * 12 + j) * X_STR + chq * 8);
                float g0 = bf2f((unsigned short)(xv.x & 0xffffu)) + bf2f((unsigned short)(a2[j].x & 0xffffu)) + Bn0;
                float g1 = bf2f((unsigned short)(xv.x >> 16))     + bf2f((unsigned short)(a2[j].x >> 16))     + Bn1;
                float g2 = bf2f((unsigned short)(xv.y & 0xffffu)) + bf2f((unsigned short)(a2[j].y & 0xffffu)) + Bn2;
                float g3 = bf2f((unsigned short)(xv.y >> 16))     + bf2f((unsigned short)(a2[j].y >> 16))     + Bn3;
                s4.x += g0; s4.y += g1; s4.z += g2; s4.w += g3;
                s24.x = fmaf(g0, g0, s24.x); s24.y = fmaf(g1, g1, s24.y);
                s24.z = fmaf(g2, g2, s24.z); s24.w = fmaf(g3, g3, s24.w);
                uint2 o; o.x = pk2(g0, g1); o.y = pk2(g2, g3);
                *(uint2*)(gated + (size_t)e * 256 + chq * 4) = o;
            }
        }
    }

    // block-level BN1 partial reduce
    __syncthreads();
    float* red = (float*)smem;
    *(float4*)(red + (size_t)(wave * 64 + chq) * 8)     = s4;
    *(float4*)(red + (size_t)(wave * 64 + chq) * 8 + 4) = s24;
    __syncthreads();
    {
        const int c = tid;
        const int g = c >> 2, k = c & 3;
        float s = 0.f, s2 = 0.f;
        #pragma unroll
        for (int w = 0; w < 4; ++w) {
            s  += red[(w * 64 + g) * 8 + k];
            s2 += red[(w * 64 + g) * 8 + 4 + k];
        }
        part[(size_t)blockIdx.x * 512 + c]       = s;
        part[(size_t)blockIdx.x * 512 + 256 + c] = s2;
    }
}

// ---- two-stage BN1 reduce -------------------------------------------------
__global__ __launch_bounds__(512) void k2b1(
    const float* __restrict__ part, float* __restrict__ out, int nRows, int rowsPerBlk)
{
    const int c = threadIdx.x;
    int r0 = blockIdx.x * rowsPerBlk;
    int r1 = min(r0 + rowsPerBlk, nRows);
    float s = 0.f;
    for (int r = r0; r < r1; ++r) s += part[(size_t)r * 512 + c];
    out[(size_t)blockIdx.x * 512 + c] = s;
}
__global__ __launch_bounds__(256) void k2b2(
    const float* __restrict__ p1, const float* __restrict__ g1v,
    const float* __restrict__ b1v, float* __restrict__ stats, float invE)
{
    const int c = threadIdx.x;
    float s = 0.f, s2 = 0.f;
    for (int r = 0; r < RB1; ++r) {
        s  += p1[(size_t)r * 512 + c];
        s2 += p1[(size_t)r * 512 + 256 + c];
    }
    float mean = s * invE;
    float var = fmaf(-mean, mean, s2 * invE);
    float sc = g1v[c] * rsqrtf(var + 1e-5f);
    stats[c] = sc;
    stats[256 + c] = fmaf(-mean, sc, b1v[c]);
}

// ---------------------------------------------------------------------------
// K3: elementwise over stored bf16 gated: BN1 affine -> sigmoid*softplus ->
// 12-edge node sum -> NS + BN2 partials.
// ---------------------------------------------------------------------------
__global__ __launch_bounds__(256) void k3_msg2(
    const unsigned short* __restrict__ gated, const float* __restrict__ stats,
    float* __restrict__ NS, float* __restrict__ part2, int nNodes)
{
    const int tid = threadIdx.x;
    const int o  = tid & 15;
    const int nl = tid >> 4;
    float scF[8], shF[8], scC[8], shC[8];
    #pragma unroll
    for (int k = 0; k < 8; ++k) {
        int cf = o * 8 + k;
        scF[k] = stats[cf];        shF[k] = stats[256 + cf];
        scC[k] = stats[128 + cf];  shC[k] = stats[384 + cf];
    }
    float sA[8] = {}, s2A[8] = {};
    for (int n = blockIdx.x * 16 + nl; n < nNodes; n += gridDim.x * 16) {
        float m[8] = {};
        for (int j = 0; j < 12; ++j) {
            size_t base = (size_t)(n * 12 + j) * 256;
            uint4 uf = *(const uint4*)(gated + base + o * 8);
            uint4 uc = *(const uint4*)(gated + base + 128 + o * 8);
            unsigned fu[4] = {uf.x, uf.y, uf.z, uf.w};
            unsigned cu[4] = {uc.x, uc.y, uc.z, uc.w};
            #pragma unroll
            for (int q = 0; q < 4; ++q) {
                float f0 = fmaf(bf2f((unsigned short)(fu[q] & 0xffffu)), scF[q*2],   shF[q*2]);
                float f1 = fmaf(bf2f((unsigned short)(fu[q] >> 16)),     scF[q*2+1], shF[q*2+1]);
                float c0 = fmaf(bf2f((unsigned short)(cu[q] & 0xffffu)), scC[q*2],   shC[q*2]);
                float c1 = fmaf(bf2f((unsigned short)(cu[q] >> 16)),     scC[q*2+1], shC[q*2+1]);
                m[q*2]   = fmaf(sigmoidf(f0), softplusf(c0), m[q*2]);
                m[q*2+1] = fmaf(sigmoidf(f1), softplusf(c1), m[q*2+1]);
            }
        }
        float4 o0 = {m[0], m[1], m[2], m[3]};
        float4 o1 = {m[4], m[5], m[6], m[7]};
        *(float4*)(NS + (size_t)n * 128 + o * 8)     = o0;
        *(float4*)(NS + (size_t)n * 128 + o * 8 + 4) = o1;
        #pragma unroll
        for (int k = 0; k < 8; ++k) {
            sA[k] += m[k];
            s2A[k] = fmaf(m[k], m[k], s2A[k]);
        }
    }
    __shared__ float red[2][16][128];
    #pragma unroll
    for (int k = 0; k < 8; ++k) {
        red[0][nl][o * 8 + k] = sA[k];
        red[1][nl][o * 8 + k] = s2A[k];
    }
    __syncthreads();
    if (tid < 128) {
        float s = 0.f, s2 = 0.f;
        #pragma unroll
        for (int r = 0; r < 16; ++r) {
            s  += red[0][r][tid];
            s2 += red[1][r][tid];
        }
        part2[(size_t)blockIdx.x * 256 + tid]       = s;
        part2[(size_t)blockIdx.x * 256 + 128 + tid] = s2;
    }
}

// ---- two-stage BN2 reduce -------------------------------------------------
__global__ __launch_bounds__(256) void k3b1(
    const float* __restrict__ part2, float* __restrict__ out, int nRows, int rowsPerBlk)
{
    const int c = threadIdx.x;
    int r0 = blockIdx.x * rowsPerBlk;
    int r1 = min(r0 + rowsPerBlk, nRows);
    float s = 0.f;
    for (int r = r0; r < r1; ++r) s += part2[(size_t)r * 256 + c];
    out[(size_t)blockIdx.x * 256 + c] = s;
}
__global__ __launch_bounds__(128) void k3b2(
    const float* __restrict__ p1, const float* __restrict__ g2v,
    const float* __restrict__ b2v, float* __restrict__ stats2, float invN)
{
    const int c = threadIdx.x;
    float s = 0.f, s2 = 0.f;
    for (int r = 0; r < RB1; ++r) {
        s  += p1[(size_t)r * 256 + c];
        s2 += p1[(size_t)r * 256 + 128 + c];
    }
    float mean = s * invN;
    float var = fmaf(-mean, mean, s2 * invN);
    float sc = g2v[c] * rsqrtf(var + 1e-5f);
    stats2[c] = sc;
    stats2[128 + c] = fmaf(-mean, sc, b2v[c]);
}

// ---------------------------------------------------------------------------
// K4: out = softplus(x + nbr_sumed*scale2 + shift2)
// ---------------------------------------------------------------------------
__global__ __launch_bounds__(256) void k4_final(
    const float* __restrict__ x, const float* __restrict__ ns,
    const float* __restrict__ stats2, float* __restrict__ out, int total4)
{
    int idx = blockIdx.x * 256 + threadIdx.x;
    for (int i = idx; i < total4; i += gridDim.x * 256) {
        int cq = i & 31;
        float4 xv = ((const float4*)x)[i];
        float4 sv = ((const float4*)ns)[i];
        float4 sc = ((const float4*)stats2)[cq];
        float4 sh = ((const float4*)(stats2 + 128))[cq];
        float4 o;
        o.x = softplusf(fmaf(sv.x, sc.x, sh.x) + xv.x);
        o.y = softplusf(fmaf(sv.y, sc.y, sh.y) + xv.y);
        o.z = softplusf(fmaf(sv.z, sc.z, sh.z) + xv.z);
        o.w = softplusf(fmaf(sv.w, sc.w, sh.w) + xv.w);
        ((float4*)out)[i] = o;
    }
}

extern "C" void kernel_launch(void* const* d_in, const int* in_sizes, int n_in,
                              void* d_out, int out_size, void* d_ws, size_t ws_size,
                              hipStream_t stream)
{
    const float* x   = (const float*)d_in[0];
    const int*   ei  = (const int*)d_in[1];
    const float* ea  = (const float*)d_in[2];
    const float* W   = (const float*)d_in[3];
    const float* b   = (const float*)d_in[4];
    const float* g1v = (const float*)d_in[5];
    const float* b1v = (const float*)d_in[6];
    const float* g2v = (const float*)d_in[7];
    const float* b2v = (const float*)d_in[8];
    float* out = (float*)d_out;

    const int nNodes = in_sizes[0] / ATOM_FEA;
    const int nEdges = in_sizes[1] / 2;

    unsigned short* Abf   = (unsigned short*)d_ws;               // nNodes*256 bf16
    unsigned short* Bbf   = Abf + (size_t)nNodes * 256;          // nNodes*256 bf16 (bias folded)
    unsigned short* gated = Bbf + (size_t)nNodes * 256;          // nEdges*256 bf16
    float* NS  = (float*)(gated + (size_t)nEdges * 256);         // nNodes*128
    float* P1  = NS  + (size_t)nNodes * 128;                     // GRID_G*512
    float* P1b = P1  + (size_t)GRID_G * 512;                     // RB1*512
    float* P2  = P1b + (size_t)RB1 * 512;                        // GRID_3*256
    float* P2b = P2  + (size_t)GRID_3 * 256;                     // RB1*256
    float* S1  = P2b + (size_t)RB1 * 256;                        // 512
    float* S2  = S1 + 512;                                       // 256
    (void)ws_size; (void)n_in; (void)out_size;

    dim3 grid1(8, (nNodes + 63) / 64);
    k1_mfma<<<grid1, 256, 0, stream>>>(x, W, b, Abf, Bbf, nNodes);

    k2_fused<<<GRID_G, 256, 0, stream>>>(Abf, Bbf, ea, ei, W, gated, P1, nNodes, nEdges);
    k2b1<<<RB1, 512, 0, stream>>>(P1, P1b, GRID_G, (GRID_G + RB1 - 1) / RB1);
    k2b2<<<1, 256, 0, stream>>>(P1b, g1v, b1v, S1, 1.f / (float)nEdges);
    k3_msg2<<<GRID_3, 256, 0, stream>>>(gated, S1, NS, P2, nNodes);
    k3b1<<<RB1, 256, 0, stream>>>(P2, P2b, GRID_3, (GRID_3 + RB1 - 1) / RB1);
    k3b2<<<1, 128, 0, stream>>>(P2b, g2v, b2v, S2, 1.f / (float)nNodes);
    k4_final<<<2048, 256, 0, stream>>>(x, NS, S2, out, nNodes * 32);
}